// Round 1
// baseline (869.561 us; speedup 1.0000x reference)
//
#include <hip/hip_runtime.h>
#include <math.h>

#define NPTS 8192
#define DCH  256
#define BB   32
#define TOTPT (BB * NPTS)            // 262144 points

// workspace layout (floats)
#define X1_OFF    0                          // 32*2*8192 = 524288
#define COS_OFF   (X1_OFF + BB * 2 * NPTS)   // 262144
#define SIN_OFF   (COS_OFF + TOTPT)          // 262144
#define X5_OFF    (SIN_OFF + TOTPT)          // 524288
#define STATS_OFF (X5_OFF + BB * 2 * NPTS)   // 128 floats: [0..63] BN1 16x4, [64..127] BN2 16x4

// ---------------------------------------------------------------------------
// block reduce (4 values) + atomic add to dst[0..3]  (dst = 16-way grouped)
// ---------------------------------------------------------------------------
__device__ __forceinline__ void block_reduce_atomic4(float v0, float v1,
                                                     float v2, float v3,
                                                     float* dst)
{
#pragma unroll
    for (int off = 32; off > 0; off >>= 1) {
        v0 += __shfl_down(v0, off, 64);
        v1 += __shfl_down(v1, off, 64);
        v2 += __shfl_down(v2, off, 64);
        v3 += __shfl_down(v3, off, 64);
    }
    __shared__ float red[4][4];
    const int wave = threadIdx.x >> 6, lane = threadIdx.x & 63;
    if (lane == 0) {
        red[wave][0] = v0; red[wave][1] = v1; red[wave][2] = v2; red[wave][3] = v3;
    }
    __syncthreads();
    if (threadIdx.x == 0) {
        float a0 = 0, a1 = 0, a2 = 0, a3 = 0;
#pragma unroll
        for (int w = 0; w < 4; ++w) {
            a0 += red[w][0]; a1 += red[w][1]; a2 += red[w][2]; a3 += red[w][3];
        }
        atomicAdd(dst + 0, a0); atomicAdd(dst + 1, a1);
        atomicAdd(dst + 2, a2); atomicAdd(dst + 3, a3);
    }
}

// ---------------------------------------------------------------------------
// Fused kernel AB (v2): heavy conv (rot 4ch + trans 2ch over feats).
// R4 theory: v1 was issue/latency-serialized by 18 global weight loads per
// channel-iteration (over SGPR budget -> interleaved waits), only ~2 B/cyc/CU
// achieved while running ALONE (FETCH_SIZE == our bytes; no concurrent
// traffic in profiled window). v2: weights staged to LDS once (broadcast
// ds_read, lgkmcnt stream), data loads batched 8 channels deep (24 global
// loads in flight per wave before first FMA). Weight LDS is reused as the
// cross-wave reduction scratch so all 4 blocks/CU stay resident (~27 KB LDS).
// Block: 256 thr = 4 waves; each wave owns 64 channels; tile = 256 points.
// ---------------------------------------------------------------------------
__global__ __launch_bounds__(256, 4) void kernAB(
    const float* __restrict__ pts, const float* __restrict__ feats,
    const float* __restrict__ rot_w, const float* __restrict__ rot_b,
    const float* __restrict__ trans_w, const float* __restrict__ trans_b,
    const float* __restrict__ pos_w, const float* __restrict__ pos_b,
    float* __restrict__ x1, float* __restrict__ cosA, float* __restrict__ sinA,
    float* __restrict__ stats)
{
    const int blk  = blockIdx.x;
    const int b    = blk >> 5;
    const int n0   = (blk & 31) << 8;
    const int tid  = threadIdx.x;
    const int wave = tid >> 6;
    const int lane = tid & 63;
    const int p    = n0 + (lane << 2);

    const float* fb = feats + (size_t)b * DCH * NPTS;

    // 20.0 KB, two lives: phase1 weights wsh[256][20], then red[3][64][25]
    __shared__ __align__(16) float shmem[5120];
    __shared__ float hw4[4][12];       // per-wave halo partial sums
    __shared__ float Tsh[6][260];      // conv result tile: idx 0..257 = n0-1..n0+256

    float (*wsh)[20] = (float (*)[20])shmem;

    // ---------------- phase 0: stage conv weights to LDS ----------------
    // wsh[c][o*3+k]; o=0..3 from rot_w, o=4..5 from trans_w. Coalesced reads.
    for (int i = tid; i < 4608; i += 256) {
        float v;
        int o, r;
        if (i < 3072) { v = rot_w[i];          o = i / 768;              r = i % 768; }
        else          { v = trans_w[i - 3072]; o = 4 + (i - 3072) / 768; r = (i - 3072) % 768; }
        const int c = r / 3, k = r % 3;
        wsh[c][o * 3 + k] = v;
    }
    __syncthreads();

    // ---------------- phase 1: main conv tile ----------------
    float acc[6][4];
#pragma unroll
    for (int o = 0; o < 6; ++o)
#pragma unroll
        for (int j = 0; j < 4; ++j) acc[o][j] = 0.0f;

    const int c0 = __builtin_amdgcn_readfirstlane(wave << 6);

    const float lmask = (p > 0) ? 1.0f : 0.0f;
    const int   lidx  = (p > 0) ? (p - 1) : 0;
    const float rmask = (p + 4 < NPTS) ? 1.0f : 0.0f;
    const int   ridx  = (p + 4 < NPTS) ? (p + 4) : 0;

    const float* fr = fb + (size_t)c0 * NPTS;

#pragma unroll 1
    for (int base = 0; base < 64; base += 8) {
        // batch-issue 24 global loads (8 channels) before any consumption
        float4 v[8]; float fl[8], fd[8];
#pragma unroll
        for (int u = 0; u < 8; ++u) {
            const float* frc = fr + (size_t)u * NPTS;
            v[u]  = *(const float4*)(frc + p);
            fl[u] = frc[lidx] * lmask;
            fd[u] = frc[ridx] * rmask;
        }
#pragma unroll
        for (int u = 0; u < 8; ++u) {
            const float* wr = wsh[c0 + base + u];   // uniform addr -> broadcast ds_read
            float w[18];
            *(float4*)(w + 0)  = *(const float4*)(wr + 0);
            *(float4*)(w + 4)  = *(const float4*)(wr + 4);
            *(float4*)(w + 8)  = *(const float4*)(wr + 8);
            *(float4*)(w + 12) = *(const float4*)(wr + 12);
            *(float2*)(w + 16) = *(const float2*)(wr + 16);
            const float f[6] = { fl[u], v[u].x, v[u].y, v[u].z, v[u].w, fd[u] };
#pragma unroll
            for (int o = 0; o < 6; ++o)
#pragma unroll
                for (int j = 0; j < 4; ++j)
                    acc[o][j] += w[o * 3] * f[j] + w[o * 3 + 1] * f[j + 1] + w[o * 3 + 2] * f[j + 2];
        }
        fr += (size_t)8 * NPTS;
    }

    // ---------------- phase 1b: halo conv points (n0-1 and n0+256) ----------
    // per-thread channel = tid; partials reduced across the block.
    float hh[12];
    {
        const float* fc = fb + (size_t)tid * NPTS;
        const int iA = (n0 >= 2) ? (n0 - 2) : 0;     // masked downstream if n0==0
        const int iB = (n0 >= 1) ? (n0 - 1) : 0;
        const float a0 = fc[iA], a1 = fc[iB], a2 = fc[n0];
        const int jB = (n0 + 256 <= NPTS - 1) ? (n0 + 256) : (NPTS - 1);
        const int jC = (n0 + 257 <= NPTS - 1) ? (n0 + 257) : (NPTS - 1);
        const float b0 = fc[n0 + 255], b1 = fc[jB], b2 = fc[jC];
        const float* wr = wsh[tid];
#pragma unroll
        for (int o = 0; o < 6; ++o) {
            const float w0 = wr[o * 3], w1 = wr[o * 3 + 1], w2 = wr[o * 3 + 2];
            hh[o]     = w0 * a0 + w1 * a1 + w2 * a2;   // left halo
            hh[6 + o] = w0 * b0 + w1 * b1 + w2 * b2;   // right halo
        }
    }
#pragma unroll
    for (int off = 32; off > 0; off >>= 1)
#pragma unroll
        for (int j = 0; j < 12; ++j)
            hh[j] += __shfl_down(hh[j], off, 64);

    // wsh is dead from here on; reuse shmem as reduction scratch.
    __syncthreads();
    float (*red)[64][25] = (float (*)[64][25])shmem;   // [3][64][25] = 4800 floats

    if (wave >= 1) {
#pragma unroll
        for (int o = 0; o < 6; ++o)
#pragma unroll
            for (int j = 0; j < 4; ++j)
                red[wave - 1][lane][o * 4 + j] = acc[o][j];
    }
    if (lane == 0) {
#pragma unroll
        for (int j = 0; j < 12; ++j) hw4[wave][j] = hh[j];
    }
    __syncthreads();

    if (wave == 0) {
#pragma unroll
        for (int q = 0; q < 3; ++q)
#pragma unroll
            for (int o = 0; o < 6; ++o)
#pragma unroll
                for (int j = 0; j < 4; ++j)
                    acc[o][j] += red[q][lane][o * 4 + j];
#pragma unroll
        for (int o = 0; o < 6; ++o) {
            const float bias = (o < 4) ? rot_b[o] : trans_b[o - 4];
#pragma unroll
            for (int j = 0; j < 4; ++j)
                Tsh[o][1 + (lane << 2) + j] = acc[o][j] + bias;
        }
    }
    if (tid < 12) {
        const int o = tid % 6, side = tid / 6;
        float v = hw4[0][tid] + hw4[1][tid] + hw4[2][tid] + hw4[3][tid];
        v += (o < 4) ? rot_b[o] : trans_b[o - 4];
        Tsh[o][side ? 257 : 0] = v;
    }
    __syncthreads();

    // ---------------- phase 2: offsets + pos-conv + rad ----------------
    const int n = n0 + tid;
    float tm[6][3];
#pragma unroll
    for (int o = 0; o < 6; ++o)
#pragma unroll
        for (int k = 0; k < 3; ++k)
            tm[o][k] = Tsh[o][tid + k];

    float xs0 = pos_b[0], xs1 = pos_b[1];
    float mz = -INFINITY;

#pragma unroll
    for (int m3 = 0; m3 < 3; ++m3) {
        const int m   = n + m3 - 1;
        const float msk = (m >= 0 && m < NPTS) ? 1.0f : 0.0f;
        const int mc  = (m < 0) ? 0 : ((m >= NPTS) ? NPTS - 1 : m);

        const float pa = pts[((size_t)b * 2 + 0) * NPTS + mc];
        const float pb = pts[((size_t)b * 2 + 1) * NPTS + mc];

        const float o0 = tm[0][m3] - 1.0f, o1 = tm[1][m3];
        const float o2 = tm[2][m3],        o3 = tm[3][m3] - 1.0f;
        const float tr0 = tm[4][m3],       tr1 = tm[5][m3];

        float p0 = pos_w[0 * 60 + 0 * 3 + m3] * pa + pos_w[0 * 60 + 1 * 3 + m3] * pb;
        float p1 = pos_w[1 * 60 + 0 * 3 + m3] * pa + pos_w[1 * 60 + 1 * 3 + m3] * pb;
#pragma unroll
        for (int k = 0; k < 9; ++k) {
            const float R0 = (float)(k / 3 - 1);
            const float R1 = (float)(k % 3 - 1);
            const float cx = o0 * R0 + o1 * R1 + tr0;
            const float cy = o2 * R0 + o3 * R1 + tr1;
            p0 += pos_w[0 * 60 + (2 + 2 * k) * 3 + m3] * cx
                + pos_w[0 * 60 + (3 + 2 * k) * 3 + m3] * cy;
            p1 += pos_w[1 * 60 + (2 + 2 * k) * 3 + m3] * cx
                + pos_w[1 * 60 + (3 + 2 * k) * 3 + m3] * cy;
            if (m3 == 1) {   // center tap: feed max-arctan (monotone => max z)
                const float z = (cy + 1e-6f) / (cx + 1e-6f);
                mz = fmaxf(mz, z);
            }
        }
        xs0 += msk * p0;
        xs1 += msk * p1;
    }

    const float mr = atanf(mz);
    float sv, cv;
    sincosf(mr, &sv, &cv);

    const int g = (b << 13) + n;
    x1[((size_t)b * 2 + 0) * NPTS + n] = xs0;
    x1[((size_t)b * 2 + 1) * NPTS + n] = xs1;
    cosA[g] = cv;
    sinA[g] = sv;

    block_reduce_atomic4(xs0, xs1, xs0 * xs0, xs1 * xs1,
                         stats + ((blk & 15) << 2));
}

// ---------------------------------------------------------------------------
// Kernel D: BN1 apply + leaky + rotate + ori-conv + BN2 stats. 1 thr/point.
// ---------------------------------------------------------------------------
__global__ __launch_bounds__(256) void kernD(
    const float* __restrict__ x1,
    const float* __restrict__ cosA, const float* __restrict__ sinA,
    const float* __restrict__ pos_g, const float* __restrict__ pos_beta,
    const float* __restrict__ ori_w, const float* __restrict__ ori_b,
    float* __restrict__ stats, float* __restrict__ x5)
{
    const int gg = blockIdx.x * 256 + threadIdx.x;
    const int b = gg >> 13;
    const int n = gg & (NPTS - 1);

    float s0 = 0, s1 = 0, s2 = 0, s3 = 0;
#pragma unroll
    for (int q = 0; q < 16; ++q) {
        s0 += stats[q * 4 + 0]; s1 += stats[q * 4 + 1];
        s2 += stats[q * 4 + 2]; s3 += stats[q * 4 + 3];
    }
    const float cntInv = 1.0f / (float)TOTPT;
    const float m0 = s0 * cntInv, m1 = s1 * cntInv;
    const float var0 = s2 * cntInv - m0 * m0;
    const float var1 = s3 * cntInv - m1 * m1;
    const float i0 = rsqrtf(var0 + 1e-5f), i1 = rsqrtf(var1 + 1e-5f);
    const float g0 = pos_g[0], g1 = pos_g[1];
    const float be0 = pos_beta[0], be1 = pos_beta[1];

    float x4a[3], x4b[3];
#pragma unroll
    for (int m3 = 0; m3 < 3; ++m3) {
        const int m   = n + m3 - 1;
        const float msk = (m >= 0 && m < NPTS) ? 1.0f : 0.0f;
        const int mc  = (m < 0) ? 0 : ((m >= NPTS) ? NPTS - 1 : m);
        float y0 = x1[((size_t)b * 2 + 0) * NPTS + mc];
        float y1 = x1[((size_t)b * 2 + 1) * NPTS + mc];
        y0 = g0 * (y0 - m0) * i0 + be0;
        y1 = g1 * (y1 - m1) * i1 + be1;
        y0 = (y0 >= 0.0f) ? y0 : 0.2f * y0;
        y1 = (y1 >= 0.0f) ? y1 : 0.2f * y1;
        const float cv = cosA[(b << 13) + mc];
        const float sv = sinA[(b << 13) + mc];
        x4a[m3] = (y0 * cv - y1 * sv) * msk;
        x4b[m3] = (y0 * sv + y1 * cv) * msk;
    }

    float z0 = ori_b[0], z1 = ori_b[1];
#pragma unroll
    for (int k = 0; k < 3; ++k) {
        z0 += ori_w[0 * 6 + 0 * 3 + k] * x4a[k] + ori_w[0 * 6 + 1 * 3 + k] * x4b[k];
        z1 += ori_w[1 * 6 + 0 * 3 + k] * x4a[k] + ori_w[1 * 6 + 1 * 3 + k] * x4b[k];
    }
    x5[((size_t)b * 2 + 0) * NPTS + n] = z0;
    x5[((size_t)b * 2 + 1) * NPTS + n] = z1;

    block_reduce_atomic4(z0, z1, z0 * z0, z1 * z1,
                         stats + 64 + ((blockIdx.x & 15) << 2));
}

// ---------------------------------------------------------------------------
// Kernel E: BN2 apply -> out
// ---------------------------------------------------------------------------
__global__ __launch_bounds__(256) void kernE(
    const float* __restrict__ x5, const float* __restrict__ stats,
    const float* __restrict__ ori_g, const float* __restrict__ ori_beta,
    float* __restrict__ out)
{
    const int gg = blockIdx.x * 256 + threadIdx.x;  // 0..524287
    const int o = (gg >> 13) & 1;
    float sm = 0, sq = 0;
#pragma unroll
    for (int q = 0; q < 16; ++q) {
        sm += stats[64 + q * 4 + o];
        sq += stats[64 + q * 4 + 2 + o];
    }
    const float cntInv = 1.0f / (float)TOTPT;
    const float m  = sm * cntInv;
    const float vv = sq * cntInv - m * m;
    const float inv = rsqrtf(vv + 1e-5f);
    out[gg] = ori_g[o] * (x5[gg] - m) * inv + ori_beta[o];
}

// ---------------------------------------------------------------------------
extern "C" void kernel_launch(void* const* d_in, const int* in_sizes, int n_in,
                              void* d_out, int out_size, void* d_ws, size_t ws_size,
                              hipStream_t stream)
{
    const float* pts      = (const float*)d_in[0];
    const float* feats    = (const float*)d_in[1];
    const float* rot_w    = (const float*)d_in[2];
    const float* rot_b    = (const float*)d_in[3];
    const float* trans_w  = (const float*)d_in[4];
    const float* trans_b  = (const float*)d_in[5];
    const float* pos_w    = (const float*)d_in[6];
    const float* pos_b    = (const float*)d_in[7];
    const float* pos_g    = (const float*)d_in[8];
    const float* pos_beta = (const float*)d_in[9];
    const float* ori_w    = (const float*)d_in[10];
    const float* ori_b    = (const float*)d_in[11];
    const float* ori_g    = (const float*)d_in[12];
    const float* ori_beta = (const float*)d_in[13];

    float* ws    = (float*)d_ws;
    float* x1    = ws + X1_OFF;
    float* cosA  = ws + COS_OFF;
    float* sinA  = ws + SIN_OFF;
    float* x5    = ws + X5_OFF;
    float* stats = ws + STATS_OFF;

    hipMemsetAsync(stats, 0, 128 * sizeof(float), stream);

    kernAB<<<1024, 256, 0, stream>>>(pts, feats, rot_w, rot_b, trans_w, trans_b,
                                     pos_w, pos_b, x1, cosA, sinA, stats);
    kernD<<<1024, 256, 0, stream>>>(x1, cosA, sinA, pos_g, pos_beta,
                                    ori_w, ori_b, stats, x5);
    kernE<<<2048, 256, 0, stream>>>(x5, stats, ori_g, ori_beta, (float*)d_out);
}

// Round 2
// 565.911 us; speedup vs baseline: 1.5366x; 1.5366x over previous
//
#include <hip/hip_runtime.h>
#include <math.h>

#define NPTS 8192
#define DCH  256
#define BB   32
#define TOTPT (BB * NPTS)            // 262144 points

// workspace layout (floats)
#define X1_OFF    0                          // 32*2*8192 = 524288
#define COS_OFF   (X1_OFF + BB * 2 * NPTS)   // 262144
#define SIN_OFF   (COS_OFF + TOTPT)          // 262144
#define X5_OFF    (SIN_OFF + TOTPT)          // 524288
#define STATS_OFF (X5_OFF + BB * 2 * NPTS)   // 128 floats: [0..63] BN1 16x4, [64..127] BN2 16x4

// ---------------------------------------------------------------------------
// block reduce (4 values) + atomic add to dst[0..3]  (dst = 16-way grouped)
// ---------------------------------------------------------------------------
__device__ __forceinline__ void block_reduce_atomic4(float v0, float v1,
                                                     float v2, float v3,
                                                     float* dst)
{
#pragma unroll
    for (int off = 32; off > 0; off >>= 1) {
        v0 += __shfl_down(v0, off, 64);
        v1 += __shfl_down(v1, off, 64);
        v2 += __shfl_down(v2, off, 64);
        v3 += __shfl_down(v3, off, 64);
    }
    __shared__ float red[4][4];
    const int wave = threadIdx.x >> 6, lane = threadIdx.x & 63;
    if (lane == 0) {
        red[wave][0] = v0; red[wave][1] = v1; red[wave][2] = v2; red[wave][3] = v3;
    }
    __syncthreads();
    if (threadIdx.x == 0) {
        float a0 = 0, a1 = 0, a2 = 0, a3 = 0;
#pragma unroll
        for (int w = 0; w < 4; ++w) {
            a0 += red[w][0]; a1 += red[w][1]; a2 += red[w][2]; a3 += red[w][3];
        }
        atomicAdd(dst + 0, a0); atomicAdd(dst + 1, a1);
        atomicAdd(dst + 2, a2); atomicAdd(dst + 3, a3);
    }
}

// per-output-channel conv update: taps (wa,wb,wc) against f0..f5
#define CONV_O(o, wa, wb, wc)                          \
    acc[o][0] += (wa) * f0 + (wb) * f1 + (wc) * f2;    \
    acc[o][1] += (wa) * f1 + (wb) * f2 + (wc) * f3;    \
    acc[o][2] += (wa) * f2 + (wb) * f3 + (wc) * f4;    \
    acc[o][3] += (wa) * f3 + (wb) * f4 + (wc) * f5;

// ---------------------------------------------------------------------------
// Fused kernel AB (v3): heavy conv (rot 4ch + trans 2ch over feats).
// R4/R5 history: v1 was latency-serialized by 18 global weight loads per
// channel (1.3 TB/s). v2 staged weights in LDS + 8-deep data batching and
// proved 3.48 TB/s streaming -- but the address-taken `float w[18]` local
// (written via *(float4*)(w+i) casts) was forced to scratch => 1.9 GB of
// spill traffic (FETCH 835 MB, WRITE 1.08 GB). v3 keeps the structure and
// reads the 18 weights into NAMED float4/float2 registers (no address-taken
// local), and drops the min-waves clamp so ~105 live VGPRs fit w/o spill.
// Block: 256 thr = 4 waves; each wave owns 64 channels; tile = 256 points.
// ---------------------------------------------------------------------------
__global__ __launch_bounds__(256) void kernAB(
    const float* __restrict__ pts, const float* __restrict__ feats,
    const float* __restrict__ rot_w, const float* __restrict__ rot_b,
    const float* __restrict__ trans_w, const float* __restrict__ trans_b,
    const float* __restrict__ pos_w, const float* __restrict__ pos_b,
    float* __restrict__ x1, float* __restrict__ cosA, float* __restrict__ sinA,
    float* __restrict__ stats)
{
    const int blk  = blockIdx.x;
    const int b    = blk >> 5;
    const int n0   = (blk & 31) << 8;
    const int tid  = threadIdx.x;
    const int wave = tid >> 6;
    const int lane = tid & 63;
    const int p    = n0 + (lane << 2);

    const float* fb = feats + (size_t)b * DCH * NPTS;

    // 20.0 KB, two lives: phase1 weights wsh[256][20], then red[3][64][25]
    __shared__ __align__(16) float shmem[5120];
    __shared__ float hw4[4][12];       // per-wave halo partial sums
    __shared__ float Tsh[6][260];      // conv result tile: idx 0..257 = n0-1..n0+256

    float (*wsh)[20] = (float (*)[20])shmem;

    // ---------------- phase 0: stage conv weights to LDS ----------------
    // wsh[c][o*3+k]; o=0..3 from rot_w, o=4..5 from trans_w. Coalesced reads.
    for (int i = tid; i < 4608; i += 256) {
        float v;
        int o, r;
        if (i < 3072) { v = rot_w[i];          o = i / 768;              r = i % 768; }
        else          { v = trans_w[i - 3072]; o = 4 + (i - 3072) / 768; r = (i - 3072) % 768; }
        const int c = r / 3, k = r % 3;
        wsh[c][o * 3 + k] = v;
    }
    __syncthreads();

    // ---------------- phase 1: main conv tile ----------------
    float acc[6][4];
#pragma unroll
    for (int o = 0; o < 6; ++o)
#pragma unroll
        for (int j = 0; j < 4; ++j) acc[o][j] = 0.0f;

    const int c0 = __builtin_amdgcn_readfirstlane(wave << 6);

    const float lmask = (p > 0) ? 1.0f : 0.0f;
    const int   lidx  = (p > 0) ? (p - 1) : 0;
    const float rmask = (p + 4 < NPTS) ? 1.0f : 0.0f;
    const int   ridx  = (p + 4 < NPTS) ? (p + 4) : 0;

    const float* fr = fb + (size_t)c0 * NPTS;

#pragma unroll 1
    for (int base = 0; base < 64; base += 8) {
        // batch-issue 24 global loads (8 channels) before any consumption
        float4 v[8]; float fl[8], fd[8];
#pragma unroll
        for (int u = 0; u < 8; ++u) {
            const float* frc = fr + (size_t)u * NPTS;
            v[u]  = *(const float4*)(frc + p);
            fl[u] = frc[lidx] * lmask;
            fd[u] = frc[ridx] * rmask;
        }
#pragma unroll
        for (int u = 0; u < 8; ++u) {
            const float* wr = wsh[c0 + base + u];   // uniform addr -> broadcast ds_read
            const float4 wA = *(const float4*)(wr + 0);    // w0..w3
            const float4 wB = *(const float4*)(wr + 4);    // w4..w7
            const float4 wC = *(const float4*)(wr + 8);    // w8..w11
            const float4 wD = *(const float4*)(wr + 12);   // w12..w15
            const float2 wE = *(const float2*)(wr + 16);   // w16..w17
            const float f0 = fl[u], f1 = v[u].x, f2 = v[u].y,
                        f3 = v[u].z, f4 = v[u].w, f5 = fd[u];
            CONV_O(0, wA.x, wA.y, wA.z)
            CONV_O(1, wA.w, wB.x, wB.y)
            CONV_O(2, wB.z, wB.w, wC.x)
            CONV_O(3, wC.y, wC.z, wC.w)
            CONV_O(4, wD.x, wD.y, wD.z)
            CONV_O(5, wD.w, wE.x, wE.y)
        }
        fr += (size_t)8 * NPTS;
    }

    // ---------------- phase 1b: halo conv points (n0-1 and n0+256) ----------
    // per-thread channel = tid; partials reduced across the block.
    float hh[12];
    {
        const float* fc = fb + (size_t)tid * NPTS;
        const int iA = (n0 >= 2) ? (n0 - 2) : 0;     // masked downstream if n0==0
        const int iB = (n0 >= 1) ? (n0 - 1) : 0;
        const float a0 = fc[iA], a1 = fc[iB], a2 = fc[n0];
        const int jB = (n0 + 256 <= NPTS - 1) ? (n0 + 256) : (NPTS - 1);
        const int jC = (n0 + 257 <= NPTS - 1) ? (n0 + 257) : (NPTS - 1);
        const float b0 = fc[n0 + 255], b1 = fc[jB], b2 = fc[jC];
        const float* wr = wsh[tid];
#pragma unroll
        for (int o = 0; o < 6; ++o) {
            const float w0 = wr[o * 3], w1 = wr[o * 3 + 1], w2 = wr[o * 3 + 2];
            hh[o]     = w0 * a0 + w1 * a1 + w2 * a2;   // left halo
            hh[6 + o] = w0 * b0 + w1 * b1 + w2 * b2;   // right halo
        }
    }
#pragma unroll
    for (int off = 32; off > 0; off >>= 1)
#pragma unroll
        for (int j = 0; j < 12; ++j)
            hh[j] += __shfl_down(hh[j], off, 64);

    // wsh is dead from here on; reuse shmem as reduction scratch.
    __syncthreads();
    float (*red)[64][25] = (float (*)[64][25])shmem;   // [3][64][25] = 4800 floats

    if (wave >= 1) {
#pragma unroll
        for (int o = 0; o < 6; ++o)
#pragma unroll
            for (int j = 0; j < 4; ++j)
                red[wave - 1][lane][o * 4 + j] = acc[o][j];
    }
    if (lane == 0) {
#pragma unroll
        for (int j = 0; j < 12; ++j) hw4[wave][j] = hh[j];
    }
    __syncthreads();

    if (wave == 0) {
#pragma unroll
        for (int q = 0; q < 3; ++q)
#pragma unroll
            for (int o = 0; o < 6; ++o)
#pragma unroll
                for (int j = 0; j < 4; ++j)
                    acc[o][j] += red[q][lane][o * 4 + j];
#pragma unroll
        for (int o = 0; o < 6; ++o) {
            const float bias = (o < 4) ? rot_b[o] : trans_b[o - 4];
#pragma unroll
            for (int j = 0; j < 4; ++j)
                Tsh[o][1 + (lane << 2) + j] = acc[o][j] + bias;
        }
    }
    if (tid < 12) {
        const int o = tid % 6, side = tid / 6;
        float v = hw4[0][tid] + hw4[1][tid] + hw4[2][tid] + hw4[3][tid];
        v += (o < 4) ? rot_b[o] : trans_b[o - 4];
        Tsh[o][side ? 257 : 0] = v;
    }
    __syncthreads();

    // ---------------- phase 2: offsets + pos-conv + rad ----------------
    const int n = n0 + tid;
    float tm[6][3];
#pragma unroll
    for (int o = 0; o < 6; ++o)
#pragma unroll
        for (int k = 0; k < 3; ++k)
            tm[o][k] = Tsh[o][tid + k];

    float xs0 = pos_b[0], xs1 = pos_b[1];
    float mz = -INFINITY;

#pragma unroll
    for (int m3 = 0; m3 < 3; ++m3) {
        const int m   = n + m3 - 1;
        const float msk = (m >= 0 && m < NPTS) ? 1.0f : 0.0f;
        const int mc  = (m < 0) ? 0 : ((m >= NPTS) ? NPTS - 1 : m);

        const float pa = pts[((size_t)b * 2 + 0) * NPTS + mc];
        const float pb = pts[((size_t)b * 2 + 1) * NPTS + mc];

        const float o0 = tm[0][m3] - 1.0f, o1 = tm[1][m3];
        const float o2 = tm[2][m3],        o3 = tm[3][m3] - 1.0f;
        const float tr0 = tm[4][m3],       tr1 = tm[5][m3];

        float p0 = pos_w[0 * 60 + 0 * 3 + m3] * pa + pos_w[0 * 60 + 1 * 3 + m3] * pb;
        float p1 = pos_w[1 * 60 + 0 * 3 + m3] * pa + pos_w[1 * 60 + 1 * 3 + m3] * pb;
#pragma unroll
        for (int k = 0; k < 9; ++k) {
            const float R0 = (float)(k / 3 - 1);
            const float R1 = (float)(k % 3 - 1);
            const float cx = o0 * R0 + o1 * R1 + tr0;
            const float cy = o2 * R0 + o3 * R1 + tr1;
            p0 += pos_w[0 * 60 + (2 + 2 * k) * 3 + m3] * cx
                + pos_w[0 * 60 + (3 + 2 * k) * 3 + m3] * cy;
            p1 += pos_w[1 * 60 + (2 + 2 * k) * 3 + m3] * cx
                + pos_w[1 * 60 + (3 + 2 * k) * 3 + m3] * cy;
            if (m3 == 1) {   // center tap: feed max-arctan (monotone => max z)
                const float z = (cy + 1e-6f) / (cx + 1e-6f);
                mz = fmaxf(mz, z);
            }
        }
        xs0 += msk * p0;
        xs1 += msk * p1;
    }

    const float mr = atanf(mz);
    float sv, cv;
    sincosf(mr, &sv, &cv);

    const int g = (b << 13) + n;
    x1[((size_t)b * 2 + 0) * NPTS + n] = xs0;
    x1[((size_t)b * 2 + 1) * NPTS + n] = xs1;
    cosA[g] = cv;
    sinA[g] = sv;

    block_reduce_atomic4(xs0, xs1, xs0 * xs0, xs1 * xs1,
                         stats + ((blk & 15) << 2));
}

// ---------------------------------------------------------------------------
// Kernel D: BN1 apply + leaky + rotate + ori-conv + BN2 stats. 1 thr/point.
// ---------------------------------------------------------------------------
__global__ __launch_bounds__(256) void kernD(
    const float* __restrict__ x1,
    const float* __restrict__ cosA, const float* __restrict__ sinA,
    const float* __restrict__ pos_g, const float* __restrict__ pos_beta,
    const float* __restrict__ ori_w, const float* __restrict__ ori_b,
    float* __restrict__ stats, float* __restrict__ x5)
{
    const int gg = blockIdx.x * 256 + threadIdx.x;
    const int b = gg >> 13;
    const int n = gg & (NPTS - 1);

    float s0 = 0, s1 = 0, s2 = 0, s3 = 0;
#pragma unroll
    for (int q = 0; q < 16; ++q) {
        s0 += stats[q * 4 + 0]; s1 += stats[q * 4 + 1];
        s2 += stats[q * 4 + 2]; s3 += stats[q * 4 + 3];
    }
    const float cntInv = 1.0f / (float)TOTPT;
    const float m0 = s0 * cntInv, m1 = s1 * cntInv;
    const float var0 = s2 * cntInv - m0 * m0;
    const float var1 = s3 * cntInv - m1 * m1;
    const float i0 = rsqrtf(var0 + 1e-5f), i1 = rsqrtf(var1 + 1e-5f);
    const float g0 = pos_g[0], g1 = pos_g[1];
    const float be0 = pos_beta[0], be1 = pos_beta[1];

    float x4a[3], x4b[3];
#pragma unroll
    for (int m3 = 0; m3 < 3; ++m3) {
        const int m   = n + m3 - 1;
        const float msk = (m >= 0 && m < NPTS) ? 1.0f : 0.0f;
        const int mc  = (m < 0) ? 0 : ((m >= NPTS) ? NPTS - 1 : m);
        float y0 = x1[((size_t)b * 2 + 0) * NPTS + mc];
        float y1 = x1[((size_t)b * 2 + 1) * NPTS + mc];
        y0 = g0 * (y0 - m0) * i0 + be0;
        y1 = g1 * (y1 - m1) * i1 + be1;
        y0 = (y0 >= 0.0f) ? y0 : 0.2f * y0;
        y1 = (y1 >= 0.0f) ? y1 : 0.2f * y1;
        const float cv = cosA[(b << 13) + mc];
        const float sv = sinA[(b << 13) + mc];
        x4a[m3] = (y0 * cv - y1 * sv) * msk;
        x4b[m3] = (y0 * sv + y1 * cv) * msk;
    }

    float z0 = ori_b[0], z1 = ori_b[1];
#pragma unroll
    for (int k = 0; k < 3; ++k) {
        z0 += ori_w[0 * 6 + 0 * 3 + k] * x4a[k] + ori_w[0 * 6 + 1 * 3 + k] * x4b[k];
        z1 += ori_w[1 * 6 + 0 * 3 + k] * x4a[k] + ori_w[1 * 6 + 1 * 3 + k] * x4b[k];
    }
    x5[((size_t)b * 2 + 0) * NPTS + n] = z0;
    x5[((size_t)b * 2 + 1) * NPTS + n] = z1;

    block_reduce_atomic4(z0, z1, z0 * z0, z1 * z1,
                         stats + 64 + ((blockIdx.x & 15) << 2));
}

// ---------------------------------------------------------------------------
// Kernel E: BN2 apply -> out
// ---------------------------------------------------------------------------
__global__ __launch_bounds__(256) void kernE(
    const float* __restrict__ x5, const float* __restrict__ stats,
    const float* __restrict__ ori_g, const float* __restrict__ ori_beta,
    float* __restrict__ out)
{
    const int gg = blockIdx.x * 256 + threadIdx.x;  // 0..524287
    const int o = (gg >> 13) & 1;
    float sm = 0, sq = 0;
#pragma unroll
    for (int q = 0; q < 16; ++q) {
        sm += stats[64 + q * 4 + o];
        sq += stats[64 + q * 4 + 2 + o];
    }
    const float cntInv = 1.0f / (float)TOTPT;
    const float m  = sm * cntInv;
    const float vv = sq * cntInv - m * m;
    const float inv = rsqrtf(vv + 1e-5f);
    out[gg] = ori_g[o] * (x5[gg] - m) * inv + ori_beta[o];
}

// ---------------------------------------------------------------------------
extern "C" void kernel_launch(void* const* d_in, const int* in_sizes, int n_in,
                              void* d_out, int out_size, void* d_ws, size_t ws_size,
                              hipStream_t stream)
{
    const float* pts      = (const float*)d_in[0];
    const float* feats    = (const float*)d_in[1];
    const float* rot_w    = (const float*)d_in[2];
    const float* rot_b    = (const float*)d_in[3];
    const float* trans_w  = (const float*)d_in[4];
    const float* trans_b  = (const float*)d_in[5];
    const float* pos_w    = (const float*)d_in[6];
    const float* pos_b    = (const float*)d_in[7];
    const float* pos_g    = (const float*)d_in[8];
    const float* pos_beta = (const float*)d_in[9];
    const float* ori_w    = (const float*)d_in[10];
    const float* ori_b    = (const float*)d_in[11];
    const float* ori_g    = (const float*)d_in[12];
    const float* ori_beta = (const float*)d_in[13];

    float* ws    = (float*)d_ws;
    float* x1    = ws + X1_OFF;
    float* cosA  = ws + COS_OFF;
    float* sinA  = ws + SIN_OFF;
    float* x5    = ws + X5_OFF;
    float* stats = ws + STATS_OFF;

    hipMemsetAsync(stats, 0, 128 * sizeof(float), stream);

    kernAB<<<1024, 256, 0, stream>>>(pts, feats, rot_w, rot_b, trans_w, trans_b,
                                     pos_w, pos_b, x1, cosA, sinA, stats);
    kernD<<<1024, 256, 0, stream>>>(x1, cosA, sinA, pos_g, pos_beta,
                                    ori_w, ori_b, stats, x5);
    kernE<<<2048, 256, 0, stream>>>(x5, stats, ori_g, ori_beta, (float*)d_out);
}

// Round 3
// 556.568 us; speedup vs baseline: 1.5624x; 1.0168x over previous
//
#include <hip/hip_runtime.h>
#include <math.h>

#define NPTS 8192
#define DCH  256
#define BB   32
#define TOTPT (BB * NPTS)            // 262144 points

// workspace layout (floats)
#define X1_OFF    0                          // 32*2*8192 = 524288
#define COS_OFF   (X1_OFF + BB * 2 * NPTS)   // 262144
#define SIN_OFF   (COS_OFF + TOTPT)          // 262144
#define X5_OFF    (SIN_OFF + TOTPT)          // 524288
#define STATS_OFF (X5_OFF + BB * 2 * NPTS)   // 128 floats
#define T_OFF     (STATS_OFF + 128)          // 32*6*8192 = 1572864 floats (6 MB)

// ---------------------------------------------------------------------------
// block reduce (4 values) + atomic add to dst[0..3]  (dst = 16-way grouped)
// ---------------------------------------------------------------------------
__device__ __forceinline__ void block_reduce_atomic4(float v0, float v1,
                                                     float v2, float v3,
                                                     float* dst)
{
#pragma unroll
    for (int off = 32; off > 0; off >>= 1) {
        v0 += __shfl_down(v0, off, 64);
        v1 += __shfl_down(v1, off, 64);
        v2 += __shfl_down(v2, off, 64);
        v3 += __shfl_down(v3, off, 64);
    }
    __shared__ float red[4][4];
    const int wave = threadIdx.x >> 6, lane = threadIdx.x & 63;
    if (lane == 0) {
        red[wave][0] = v0; red[wave][1] = v1; red[wave][2] = v2; red[wave][3] = v3;
    }
    __syncthreads();
    if (threadIdx.x == 0) {
        float a0 = 0, a1 = 0, a2 = 0, a3 = 0;
#pragma unroll
        for (int w = 0; w < 4; ++w) {
            a0 += red[w][0]; a1 += red[w][1]; a2 += red[w][2]; a3 += red[w][3];
        }
        atomicAdd(dst + 0, a0); atomicAdd(dst + 1, a1);
        atomicAdd(dst + 2, a2); atomicAdd(dst + 3, a3);
    }
}

// per-output-channel conv update: taps (wa,wb,wc) against f0..f5
#define CONV_O(o, wa, wb, wc)                          \
    acc[o][0] += (wa) * f0 + (wb) * f1 + (wc) * f2;    \
    acc[o][1] += (wa) * f1 + (wb) * f2 + (wc) * f3;    \
    acc[o][2] += (wa) * f2 + (wb) * f3 + (wc) * f4;    \
    acc[o][3] += (wa) * f3 + (wb) * f4 + (wc) * f5;

// ---------------------------------------------------------------------------
// kernT (v4): the heavy conv restructured as stage->LDS->compute->atomicAdd.
// R6 theory: v1/v3 were latency-serialized (per-CU in-flight ~1.5 KB; the
// in-loop "batched" loads resolve serially because the scheduler interleaves
// waits with consumption). Fix: a pure staging phase (8 back-to-back float4
// loads/wave -> LDS, zero arithmetic between) + 8x grid via channel-split.
// Grid: 8192 blocks = 8 cg x 32 b x 32 tiles. Block: 256 thr = 4 waves.
// Each block: stage 32 rows x 264 floats (halos stored, zeros at bounds),
// each wave computes 8 channels x 256 points from LDS, cross-wave reduce,
// wave0 atomicAdds 6x256 partials into T[b][6][n] (no-return atomics).
// ---------------------------------------------------------------------------
__global__ __launch_bounds__(256) void kernT(
    const float* __restrict__ feats,
    const float* __restrict__ rot_w, const float* __restrict__ trans_w,
    float* __restrict__ T)
{
    const int blk  = blockIdx.x;
    const int cg   = blk >> 10;         // 8 channel groups (outer: separates atomic contenders in time)
    const int b    = (blk >> 5) & 31;
    const int tile = blk & 31;
    const int n0   = tile << 8;
    const int c0g  = cg << 5;           // first channel of this group's 32
    const int tid  = threadIdx.x;
    const int wave = tid >> 6;
    const int lane = tid & 63;
    const int q    = lane << 2;         // 4 points per lane

    // fsh[r][j] = feats[c0g+r][n0-4+j]; valid j in [3,260]; [4,259] from main loads
    __shared__ __align__(16) float fsh[32][264];   // 33792 B
    __shared__ __align__(16) float wsh[32][20];    //  2560 B (18 used, pad->16B-aligned rows)

    const float* fb = feats + (size_t)b * DCH * NPTS;

    // ---- stage weights (576 dwords, once) ----
    for (int i = tid; i < 576; i += 256) {
        const int c = i / 18, t = i % 18, o = t / 3, k = t % 3;
        const int C = c0g + c;
        wsh[c][t] = (o < 4) ? rot_w[((size_t)o * DCH + C) * 3 + k]
                            : trans_w[((size_t)(o - 4) * DCH + C) * 3 + k];
    }

    // ---- stage data: wave w loads rows 8w..8w+7, batch 8 loads THEN 8 writes ----
    {
        float4 t[8];
#pragma unroll
        for (int rr = 0; rr < 8; ++rr) {
            const int r = (wave << 3) + rr;
            t[rr] = *(const float4*)(fb + (size_t)(c0g + r) * NPTS + n0 + q);
        }
#pragma unroll
        for (int rr = 0; rr < 8; ++rr) {
            const int r = (wave << 3) + rr;
            *(float4*)&fsh[r][4 + q] = t[rr];
        }
        // halos: lanes 0..7 left (j=3), lanes 8..15 right (j=260); zero-pad at bounds
        if (lane < 16) {
            const int r    = (wave << 3) + (lane & 7);
            const int side = lane >> 3;
            float v = 0.0f;
            if (side == 0) {
                if (n0 > 0) v = fb[(size_t)(c0g + r) * NPTS + n0 - 1];
                fsh[r][3] = v;
            } else {
                if (n0 + 256 < NPTS) v = fb[(size_t)(c0g + r) * NPTS + n0 + 256];
                fsh[r][260] = v;
            }
        }
    }
    __syncthreads();

    // ---- compute: each wave its 8 channels, all 256 points ----
    float acc[6][4];
#pragma unroll
    for (int o = 0; o < 6; ++o)
#pragma unroll
        for (int j = 0; j < 4; ++j) acc[o][j] = 0.0f;

#pragma unroll
    for (int cc = 0; cc < 8; ++cc) {
        const int r = (wave << 3) + cc;
        const float* wr = wsh[r];                       // uniform -> broadcast ds_read
        const float4 wA = *(const float4*)(wr + 0);
        const float4 wB = *(const float4*)(wr + 4);
        const float4 wC = *(const float4*)(wr + 8);
        const float4 wD = *(const float4*)(wr + 12);
        const float2 wE = *(const float2*)(wr + 16);
        const float* dr = &fsh[r][0];
        const float4 dA = *(const float4*)(dr + q);      // j = q..q+3   (need .w = f[n-1])
        const float4 dB = *(const float4*)(dr + q + 4);  // j = q+4..q+7 (f[n..n+3])
        const float4 dC = *(const float4*)(dr + q + 8);  // j = q+8..    (need .x = f[n+4])
        const float f0 = dA.w, f1 = dB.x, f2 = dB.y,
                    f3 = dB.z, f4 = dB.w, f5 = dC.x;
        CONV_O(0, wA.x, wA.y, wA.z)
        CONV_O(1, wA.w, wB.x, wB.y)
        CONV_O(2, wB.z, wB.w, wC.x)
        CONV_O(3, wC.y, wC.z, wC.w)
        CONV_O(4, wD.x, wD.y, wD.z)
        CONV_O(5, wD.w, wE.x, wE.y)
    }

    // ---- cross-wave reduce (overlay scratch on dead fsh) ----
    __syncthreads();
    float (*red)[64][25] = (float (*)[64][25])&fsh[0][0];   // 4800 floats < 8448
    if (wave >= 1) {
#pragma unroll
        for (int o = 0; o < 6; ++o)
#pragma unroll
            for (int j = 0; j < 4; ++j)
                red[wave - 1][lane][o * 4 + j] = acc[o][j];
    }
    __syncthreads();

    if (wave == 0) {
#pragma unroll
        for (int w = 0; w < 3; ++w)
#pragma unroll
            for (int o = 0; o < 6; ++o)
#pragma unroll
                for (int j = 0; j < 4; ++j)
                    acc[o][j] += red[w][lane][o * 4 + j];
        // no-return atomics: fire-and-forget partial accumulation into T
#pragma unroll
        for (int o = 0; o < 6; ++o)
#pragma unroll
            for (int j = 0; j < 4; ++j)
                atomicAdd(&T[(((size_t)b * 6 + o) << 13) + n0 + q + j], acc[o][j]);
    }
}

// ---------------------------------------------------------------------------
// kernA2: phase-2 (offset expansion + pos-conv + max-arctan + sincos) from T.
// T is 6 MB -> L2/L3-hot. 1 thr/point. Also BN1 stats.
// ---------------------------------------------------------------------------
__global__ __launch_bounds__(256) void kernA2(
    const float* __restrict__ T, const float* __restrict__ pts,
    const float* __restrict__ rot_b, const float* __restrict__ trans_b,
    const float* __restrict__ pos_w, const float* __restrict__ pos_b,
    float* __restrict__ x1, float* __restrict__ cosA, float* __restrict__ sinA,
    float* __restrict__ stats)
{
    const int gg = blockIdx.x * 256 + threadIdx.x;
    const int b  = gg >> 13;
    const int n  = gg & (NPTS - 1);

    const float bias0 = rot_b[0], bias1 = rot_b[1], bias2 = rot_b[2], bias3 = rot_b[3];
    const float bias4 = trans_b[0], bias5 = trans_b[1];

    float tm[6][3];
#pragma unroll
    for (int m3 = 0; m3 < 3; ++m3) {
        const int m  = n + m3 - 1;
        const int mc = (m < 0) ? 0 : ((m >= NPTS) ? NPTS - 1 : m);
        tm[0][m3] = T[(((size_t)b * 6 + 0) << 13) + mc] + bias0;
        tm[1][m3] = T[(((size_t)b * 6 + 1) << 13) + mc] + bias1;
        tm[2][m3] = T[(((size_t)b * 6 + 2) << 13) + mc] + bias2;
        tm[3][m3] = T[(((size_t)b * 6 + 3) << 13) + mc] + bias3;
        tm[4][m3] = T[(((size_t)b * 6 + 4) << 13) + mc] + bias4;
        tm[5][m3] = T[(((size_t)b * 6 + 5) << 13) + mc] + bias5;
    }

    float xs0 = pos_b[0], xs1 = pos_b[1];
    float mz = -INFINITY;

#pragma unroll
    for (int m3 = 0; m3 < 3; ++m3) {
        const int m   = n + m3 - 1;
        const float msk = (m >= 0 && m < NPTS) ? 1.0f : 0.0f;
        const int mc  = (m < 0) ? 0 : ((m >= NPTS) ? NPTS - 1 : m);

        const float pa = pts[((size_t)b * 2 + 0) * NPTS + mc];
        const float pb = pts[((size_t)b * 2 + 1) * NPTS + mc];

        const float o0 = tm[0][m3] - 1.0f, o1 = tm[1][m3];
        const float o2 = tm[2][m3],        o3 = tm[3][m3] - 1.0f;
        const float tr0 = tm[4][m3],       tr1 = tm[5][m3];

        float p0 = pos_w[0 * 60 + 0 * 3 + m3] * pa + pos_w[0 * 60 + 1 * 3 + m3] * pb;
        float p1 = pos_w[1 * 60 + 0 * 3 + m3] * pa + pos_w[1 * 60 + 1 * 3 + m3] * pb;
#pragma unroll
        for (int k = 0; k < 9; ++k) {
            const float R0 = (float)(k / 3 - 1);
            const float R1 = (float)(k % 3 - 1);
            const float cx = o0 * R0 + o1 * R1 + tr0;
            const float cy = o2 * R0 + o3 * R1 + tr1;
            p0 += pos_w[0 * 60 + (2 + 2 * k) * 3 + m3] * cx
                + pos_w[0 * 60 + (3 + 2 * k) * 3 + m3] * cy;
            p1 += pos_w[1 * 60 + (2 + 2 * k) * 3 + m3] * cx
                + pos_w[1 * 60 + (3 + 2 * k) * 3 + m3] * cy;
            if (m3 == 1) {   // center tap: feed max-arctan (monotone => max z)
                const float z = (cy + 1e-6f) / (cx + 1e-6f);
                mz = fmaxf(mz, z);
            }
        }
        xs0 += msk * p0;
        xs1 += msk * p1;
    }

    const float mr = atanf(mz);
    float sv, cv;
    sincosf(mr, &sv, &cv);

    x1[((size_t)b * 2 + 0) * NPTS + n] = xs0;
    x1[((size_t)b * 2 + 1) * NPTS + n] = xs1;
    cosA[gg] = cv;
    sinA[gg] = sv;

    block_reduce_atomic4(xs0, xs1, xs0 * xs0, xs1 * xs1,
                         stats + ((blockIdx.x & 15) << 2));
}

// ---------------------------------------------------------------------------
// Kernel D: BN1 apply + leaky + rotate + ori-conv + BN2 stats. 1 thr/point.
// ---------------------------------------------------------------------------
__global__ __launch_bounds__(256) void kernD(
    const float* __restrict__ x1,
    const float* __restrict__ cosA, const float* __restrict__ sinA,
    const float* __restrict__ pos_g, const float* __restrict__ pos_beta,
    const float* __restrict__ ori_w, const float* __restrict__ ori_b,
    float* __restrict__ stats, float* __restrict__ x5)
{
    const int gg = blockIdx.x * 256 + threadIdx.x;
    const int b = gg >> 13;
    const int n = gg & (NPTS - 1);

    float s0 = 0, s1 = 0, s2 = 0, s3 = 0;
#pragma unroll
    for (int q = 0; q < 16; ++q) {
        s0 += stats[q * 4 + 0]; s1 += stats[q * 4 + 1];
        s2 += stats[q * 4 + 2]; s3 += stats[q * 4 + 3];
    }
    const float cntInv = 1.0f / (float)TOTPT;
    const float m0 = s0 * cntInv, m1 = s1 * cntInv;
    const float var0 = s2 * cntInv - m0 * m0;
    const float var1 = s3 * cntInv - m1 * m1;
    const float i0 = rsqrtf(var0 + 1e-5f), i1 = rsqrtf(var1 + 1e-5f);
    const float g0 = pos_g[0], g1 = pos_g[1];
    const float be0 = pos_beta[0], be1 = pos_beta[1];

    float x4a[3], x4b[3];
#pragma unroll
    for (int m3 = 0; m3 < 3; ++m3) {
        const int m   = n + m3 - 1;
        const float msk = (m >= 0 && m < NPTS) ? 1.0f : 0.0f;
        const int mc  = (m < 0) ? 0 : ((m >= NPTS) ? NPTS - 1 : m);
        float y0 = x1[((size_t)b * 2 + 0) * NPTS + mc];
        float y1 = x1[((size_t)b * 2 + 1) * NPTS + mc];
        y0 = g0 * (y0 - m0) * i0 + be0;
        y1 = g1 * (y1 - m1) * i1 + be1;
        y0 = (y0 >= 0.0f) ? y0 : 0.2f * y0;
        y1 = (y1 >= 0.0f) ? y1 : 0.2f * y1;
        const float cv = cosA[(b << 13) + mc];
        const float sv = sinA[(b << 13) + mc];
        x4a[m3] = (y0 * cv - y1 * sv) * msk;
        x4b[m3] = (y0 * sv + y1 * cv) * msk;
    }

    float z0 = ori_b[0], z1 = ori_b[1];
#pragma unroll
    for (int k = 0; k < 3; ++k) {
        z0 += ori_w[0 * 6 + 0 * 3 + k] * x4a[k] + ori_w[0 * 6 + 1 * 3 + k] * x4b[k];
        z1 += ori_w[1 * 6 + 0 * 3 + k] * x4a[k] + ori_w[1 * 6 + 1 * 3 + k] * x4b[k];
    }
    x5[((size_t)b * 2 + 0) * NPTS + n] = z0;
    x5[((size_t)b * 2 + 1) * NPTS + n] = z1;

    block_reduce_atomic4(z0, z1, z0 * z0, z1 * z1,
                         stats + 64 + ((blockIdx.x & 15) << 2));
}

// ---------------------------------------------------------------------------
// Kernel E: BN2 apply -> out
// ---------------------------------------------------------------------------
__global__ __launch_bounds__(256) void kernE(
    const float* __restrict__ x5, const float* __restrict__ stats,
    const float* __restrict__ ori_g, const float* __restrict__ ori_beta,
    float* __restrict__ out)
{
    const int gg = blockIdx.x * 256 + threadIdx.x;  // 0..524287
    const int o = (gg >> 13) & 1;
    float sm = 0, sq = 0;
#pragma unroll
    for (int q = 0; q < 16; ++q) {
        sm += stats[64 + q * 4 + o];
        sq += stats[64 + q * 4 + 2 + o];
    }
    const float cntInv = 1.0f / (float)TOTPT;
    const float m  = sm * cntInv;
    const float vv = sq * cntInv - m * m;
    const float inv = rsqrtf(vv + 1e-5f);
    out[gg] = ori_g[o] * (x5[gg] - m) * inv + ori_beta[o];
}

// ---------------------------------------------------------------------------
extern "C" void kernel_launch(void* const* d_in, const int* in_sizes, int n_in,
                              void* d_out, int out_size, void* d_ws, size_t ws_size,
                              hipStream_t stream)
{
    const float* pts      = (const float*)d_in[0];
    const float* feats    = (const float*)d_in[1];
    const float* rot_w    = (const float*)d_in[2];
    const float* rot_b    = (const float*)d_in[3];
    const float* trans_w  = (const float*)d_in[4];
    const float* trans_b  = (const float*)d_in[5];
    const float* pos_w    = (const float*)d_in[6];
    const float* pos_b    = (const float*)d_in[7];
    const float* pos_g    = (const float*)d_in[8];
    const float* pos_beta = (const float*)d_in[9];
    const float* ori_w    = (const float*)d_in[10];
    const float* ori_b    = (const float*)d_in[11];
    const float* ori_g    = (const float*)d_in[12];
    const float* ori_beta = (const float*)d_in[13];

    float* ws    = (float*)d_ws;
    float* x1    = ws + X1_OFF;
    float* cosA  = ws + COS_OFF;
    float* sinA  = ws + SIN_OFF;
    float* x5    = ws + X5_OFF;
    float* stats = ws + STATS_OFF;
    float* T     = ws + T_OFF;

    // zero stats (128 floats) + T (6 MB) in one memset (adjacent regions)
    hipMemsetAsync(stats, 0, (128 + (size_t)BB * 6 * NPTS) * sizeof(float), stream);

    kernT<<<8192, 256, 0, stream>>>(feats, rot_w, trans_w, T);
    kernA2<<<1024, 256, 0, stream>>>(T, pts, rot_b, trans_b, pos_w, pos_b,
                                     x1, cosA, sinA, stats);
    kernD<<<1024, 256, 0, stream>>>(x1, cosA, sinA, pos_g, pos_beta,
                                    ori_w, ori_b, stats, x5);
    kernE<<<2048, 256, 0, stream>>>(x5, stats, ori_g, ori_beta, (float*)d_out);
}

// Round 4
// 433.235 us; speedup vs baseline: 2.0071x; 1.2847x over previous
//
#include <hip/hip_runtime.h>
#include <math.h>

#define NPTS 8192
#define DCH  256
#define BB   32
#define TOTPT (BB * NPTS)            // 262144 points

// workspace layout (floats)
#define X1_OFF    0                          // 32*2*8192 = 524288
#define COS_OFF   (X1_OFF + BB * 2 * NPTS)   // 262144
#define SIN_OFF   (COS_OFF + TOTPT)          // 262144
#define X5_OFF    (SIN_OFF + TOTPT)          // 524288
#define STATS_OFF (X5_OFF + BB * 2 * NPTS)   // 128 floats

// ---------------------------------------------------------------------------
// block reduce (4 values) + atomic add to dst[0..3]  (dst = 16-way grouped)
// ---------------------------------------------------------------------------
__device__ __forceinline__ void block_reduce_atomic4(float v0, float v1,
                                                     float v2, float v3,
                                                     float* dst)
{
#pragma unroll
    for (int off = 32; off > 0; off >>= 1) {
        v0 += __shfl_down(v0, off, 64);
        v1 += __shfl_down(v1, off, 64);
        v2 += __shfl_down(v2, off, 64);
        v3 += __shfl_down(v3, off, 64);
    }
    __shared__ float red[4][4];
    const int wave = threadIdx.x >> 6, lane = threadIdx.x & 63;
    if (lane == 0) {
        red[wave][0] = v0; red[wave][1] = v1; red[wave][2] = v2; red[wave][3] = v3;
    }
    __syncthreads();
    if (threadIdx.x == 0) {
        float a0 = 0, a1 = 0, a2 = 0, a3 = 0;
#pragma unroll
        for (int w = 0; w < 4; ++w) {
            a0 += red[w][0]; a1 += red[w][1]; a2 += red[w][2]; a3 += red[w][3];
        }
        atomicAdd(dst + 0, a0); atomicAdd(dst + 1, a1);
        atomicAdd(dst + 2, a2); atomicAdd(dst + 3, a3);
    }
}

// per-output-channel conv update: taps (wa,wb,wc) against f0..f5
#define CONV_O(o, wa, wb, wc)                          \
    acc[o][0] += (wa) * f0 + (wb) * f1 + (wc) * f2;    \
    acc[o][1] += (wa) * f1 + (wb) * f2 + (wc) * f3;    \
    acc[o][2] += (wa) * f2 + (wb) * f3 + (wc) * f4;    \
    acc[o][3] += (wa) * f3 + (wb) * f4 + (wc) * f5;

// ---------------------------------------------------------------------------
// kernAB (v5): fused conv + offsets + pos-conv + rad. One block per (b,tile).
// R7 design: v1/v3 were latency-serialized (compute consumed loaded regs ->
// scheduler interleaved vmcnt waits, ~1.5KB in flight/CU). v4's atomic sink
// added 4x write amplification + serialized block retirement. v5: 16 chunks
// of 16 channels, double-buffered LDS staging. Per chunk each wave stages 4
// rows (4 coalesced float4/lane burst) incl. halo cols; computes PREVIOUS
// chunk from LDS; vmcnt wait sits only at the ds_write AFTER compute (T14
// issue-early/write-late) so HBM latency hides under compute structurally.
// No global T, no atomics; phase 1b / reduce / Tsh / phase 2 verbatim v3.
// LDS ~59KB -> 2 blocks/CU; in-flight 33.8KB/CU >> 9KB Little's-law need.
// ---------------------------------------------------------------------------
__global__ __launch_bounds__(256) void kernAB(
    const float* __restrict__ pts, const float* __restrict__ feats,
    const float* __restrict__ rot_w, const float* __restrict__ rot_b,
    const float* __restrict__ trans_w, const float* __restrict__ trans_b,
    const float* __restrict__ pos_w, const float* __restrict__ pos_b,
    float* __restrict__ x1, float* __restrict__ cosA, float* __restrict__ sinA,
    float* __restrict__ stats)
{
    const int blk  = blockIdx.x;
    const int b    = blk >> 5;
    const int n0   = (blk & 31) << 8;
    const int tid  = threadIdx.x;
    const int wave = tid >> 6;
    const int lane = tid & 63;
    const int q    = lane << 2;          // 4 points per lane

    const float* fb = feats + (size_t)b * DCH * NPTS;

    // fsh[buf][r][j] = feats[chunk*16+r][n0-4+j]; main j=4..259, halo j=2,3,260,261
    __shared__ __align__(16) float fsh[2][16][264];   // 33792 B
    __shared__ __align__(16) float wsh_mem[256 * 20]; // 20480 B; overlaid by red later
    __shared__ float hw4[4][12];
    __shared__ float Tsh[6][260];        // conv tile: idx 0..257 = n0-1..n0+256

    float (*wsh)[20] = (float (*)[20])wsh_mem;

    // ---- phase 1b loads issued early (channel = tid); consumed after loop ----
    const float* fc = fb + (size_t)tid * NPTS;
    const int iA = (n0 >= 2) ? (n0 - 2) : 0;     // masked downstream if n0==0
    const int iB = (n0 >= 1) ? (n0 - 1) : 0;
    const float ha0 = fc[iA], ha1 = fc[iB], ha2 = fc[n0];
    const int jB = (n0 + 256 <= NPTS - 1) ? (n0 + 256) : (NPTS - 1);
    const int jC = (n0 + 257 <= NPTS - 1) ? (n0 + 257) : (NPTS - 1);
    const float hb0 = fc[n0 + 255], hb1 = fc[jB], hb2 = fc[jC];

    // ---- stage weights to LDS: wsh[c][o*3+k] ----
    for (int i = tid; i < 4608; i += 256) {
        float v; int o, r;
        if (i < 3072) { v = rot_w[i];          o = i / 768;              r = i % 768; }
        else          { v = trans_w[i - 3072]; o = 4 + (i - 3072) / 768; r = (i - 3072) % 768; }
        wsh[r / 3][o * 3 + (r % 3)] = v;
    }

    // ---- chunked double-buffered staging ----
    const int  r0       = wave << 2;         // this wave's first row in chunk
    const bool haloLane = (lane < 8);
    const int  hrr      = lane & 3;
    const int  hside    = lane >> 2;         // 0=left (j=2..3), 1=right (j=260..261)

    float4 t0, t1, t2, t3; float2 hl;

#define STAGE_LOAD(c) {                                                        \
        const float* gp = fb + (size_t)((c) * 16 + r0) * NPTS + n0 + q;        \
        t0 = *(const float4*)(gp);                                             \
        t1 = *(const float4*)(gp + NPTS);                                      \
        t2 = *(const float4*)(gp + 2 * NPTS);                                  \
        t3 = *(const float4*)(gp + 3 * NPTS);                                  \
        hl = make_float2(0.0f, 0.0f);                                          \
        if (haloLane) {                                                        \
            const size_t hb_ = (size_t)((c) * 16 + r0 + hrr) * NPTS;           \
            if (hside == 0) { if (n0 > 0)          hl = *(const float2*)(fb + hb_ + n0 - 2); } \
            else            { if (n0 + 257 < NPTS) hl = *(const float2*)(fb + hb_ + n0 + 256); } \
        } }

#define STAGE_WRITE(c) {                                                       \
        const int bw_ = (c) & 1;                                               \
        *(float4*)&fsh[bw_][r0 + 0][4 + q] = t0;                               \
        *(float4*)&fsh[bw_][r0 + 1][4 + q] = t1;                               \
        *(float4*)&fsh[bw_][r0 + 2][4 + q] = t2;                               \
        *(float4*)&fsh[bw_][r0 + 3][4 + q] = t3;                               \
        if (haloLane) *(float2*)&fsh[bw_][r0 + hrr][hside ? 260 : 2] = hl; }

    STAGE_LOAD(0)
    STAGE_WRITE(0)
    __syncthreads();   // wsh + chunk0 visible

    float acc[6][4];
#pragma unroll
    for (int o = 0; o < 6; ++o)
#pragma unroll
        for (int j = 0; j < 4; ++j) acc[o][j] = 0.0f;

#pragma unroll 1
    for (int c = 0; c < 16; ++c) {
        if (c < 15) STAGE_LOAD(c + 1)          // issue next-chunk loads first
        {
            const int bufr = c & 1;
#pragma unroll
            for (int rr = 0; rr < 4; ++rr) {
                const int ch = c * 16 + r0 + rr;
                const float* wr = wsh[ch];                 // uniform -> broadcast
                const float4 wA = *(const float4*)(wr + 0);
                const float4 wB = *(const float4*)(wr + 4);
                const float4 wC = *(const float4*)(wr + 8);
                const float4 wD = *(const float4*)(wr + 12);
                const float2 wE = *(const float2*)(wr + 16);
                const float* dr = &fsh[bufr][r0 + rr][0];
                const float4 dA = *(const float4*)(dr + q);      // .w = f[n-1]
                const float4 dB = *(const float4*)(dr + q + 4);  // f[n..n+3]
                const float4 dC = *(const float4*)(dr + q + 8);  // .x = f[n+4]
                const float f0 = dA.w, f1 = dB.x, f2 = dB.y,
                            f3 = dB.z, f4 = dB.w, f5 = dC.x;
                CONV_O(0, wA.x, wA.y, wA.z)
                CONV_O(1, wA.w, wB.x, wB.y)
                CONV_O(2, wB.z, wB.w, wC.x)
                CONV_O(3, wC.y, wC.z, wC.w)
                CONV_O(4, wD.x, wD.y, wD.z)
                CONV_O(5, wD.w, wE.x, wE.y)
            }
        }
        if (c < 15) STAGE_WRITE(c + 1)         // vmcnt wait lands HERE, after compute
        __syncthreads();
    }

    // ---- phase 1b compute (wsh still intact; ha*/hb* loaded long ago) ----
    float hh[12];
    {
        const float* wrh = wsh[tid];
#pragma unroll
        for (int o = 0; o < 6; ++o) {
            const float w0 = wrh[o * 3], w1 = wrh[o * 3 + 1], w2 = wrh[o * 3 + 2];
            hh[o]     = w0 * ha0 + w1 * ha1 + w2 * ha2;   // left halo (n0-1)
            hh[6 + o] = w0 * hb0 + w1 * hb1 + w2 * hb2;   // right halo (n0+256)
        }
    }
#pragma unroll
    for (int off = 32; off > 0; off >>= 1)
#pragma unroll
        for (int j = 0; j < 12; ++j)
            hh[j] += __shfl_down(hh[j], off, 64);

    // wsh dead from here; overlay reduction scratch
    __syncthreads();
    float (*red)[64][25] = (float (*)[64][25])wsh_mem;   // 4800 floats <= 5120

    if (wave >= 1) {
#pragma unroll
        for (int o = 0; o < 6; ++o)
#pragma unroll
            for (int j = 0; j < 4; ++j)
                red[wave - 1][lane][o * 4 + j] = acc[o][j];
    }
    if (lane == 0) {
#pragma unroll
        for (int j = 0; j < 12; ++j) hw4[wave][j] = hh[j];
    }
    __syncthreads();

    if (wave == 0) {
#pragma unroll
        for (int w = 0; w < 3; ++w)
#pragma unroll
            for (int o = 0; o < 6; ++o)
#pragma unroll
                for (int j = 0; j < 4; ++j)
                    acc[o][j] += red[w][lane][o * 4 + j];
#pragma unroll
        for (int o = 0; o < 6; ++o) {
            const float bias = (o < 4) ? rot_b[o] : trans_b[o - 4];
#pragma unroll
            for (int j = 0; j < 4; ++j)
                Tsh[o][1 + (lane << 2) + j] = acc[o][j] + bias;
        }
    }
    if (tid < 12) {
        const int o = tid % 6, side = tid / 6;
        float v = hw4[0][tid] + hw4[1][tid] + hw4[2][tid] + hw4[3][tid];
        v += (o < 4) ? rot_b[o] : trans_b[o - 4];
        Tsh[o][side ? 257 : 0] = v;
    }
    __syncthreads();

    // ---------------- phase 2: offsets + pos-conv + rad ----------------
    const int n = n0 + tid;
    float tm[6][3];
#pragma unroll
    for (int o = 0; o < 6; ++o)
#pragma unroll
        for (int k = 0; k < 3; ++k)
            tm[o][k] = Tsh[o][tid + k];

    float xs0 = pos_b[0], xs1 = pos_b[1];
    float mz = -INFINITY;

#pragma unroll
    for (int m3 = 0; m3 < 3; ++m3) {
        const int m   = n + m3 - 1;
        const float msk = (m >= 0 && m < NPTS) ? 1.0f : 0.0f;
        const int mc  = (m < 0) ? 0 : ((m >= NPTS) ? NPTS - 1 : m);

        const float pa = pts[((size_t)b * 2 + 0) * NPTS + mc];
        const float pb = pts[((size_t)b * 2 + 1) * NPTS + mc];

        const float o0 = tm[0][m3] - 1.0f, o1 = tm[1][m3];
        const float o2 = tm[2][m3],        o3 = tm[3][m3] - 1.0f;
        const float tr0 = tm[4][m3],       tr1 = tm[5][m3];

        float p0 = pos_w[0 * 60 + 0 * 3 + m3] * pa + pos_w[0 * 60 + 1 * 3 + m3] * pb;
        float p1 = pos_w[1 * 60 + 0 * 3 + m3] * pa + pos_w[1 * 60 + 1 * 3 + m3] * pb;
#pragma unroll
        for (int k = 0; k < 9; ++k) {
            const float R0 = (float)(k / 3 - 1);
            const float R1 = (float)(k % 3 - 1);
            const float cx = o0 * R0 + o1 * R1 + tr0;
            const float cy = o2 * R0 + o3 * R1 + tr1;
            p0 += pos_w[0 * 60 + (2 + 2 * k) * 3 + m3] * cx
                + pos_w[0 * 60 + (3 + 2 * k) * 3 + m3] * cy;
            p1 += pos_w[1 * 60 + (2 + 2 * k) * 3 + m3] * cx
                + pos_w[1 * 60 + (3 + 2 * k) * 3 + m3] * cy;
            if (m3 == 1) {   // center tap: feed max-arctan (monotone => max z)
                const float z = (cy + 1e-6f) / (cx + 1e-6f);
                mz = fmaxf(mz, z);
            }
        }
        xs0 += msk * p0;
        xs1 += msk * p1;
    }

    const float mr = atanf(mz);
    float sv, cv;
    sincosf(mr, &sv, &cv);

    const int g = (b << 13) + n;
    x1[((size_t)b * 2 + 0) * NPTS + n] = xs0;
    x1[((size_t)b * 2 + 1) * NPTS + n] = xs1;
    cosA[g] = cv;
    sinA[g] = sv;

    block_reduce_atomic4(xs0, xs1, xs0 * xs0, xs1 * xs1,
                         stats + ((blk & 15) << 2));
}

// ---------------------------------------------------------------------------
// Kernel D: BN1 apply + leaky + rotate + ori-conv + BN2 stats. 1 thr/point.
// ---------------------------------------------------------------------------
__global__ __launch_bounds__(256) void kernD(
    const float* __restrict__ x1,
    const float* __restrict__ cosA, const float* __restrict__ sinA,
    const float* __restrict__ pos_g, const float* __restrict__ pos_beta,
    const float* __restrict__ ori_w, const float* __restrict__ ori_b,
    float* __restrict__ stats, float* __restrict__ x5)
{
    const int gg = blockIdx.x * 256 + threadIdx.x;
    const int b = gg >> 13;
    const int n = gg & (NPTS - 1);

    float s0 = 0, s1 = 0, s2 = 0, s3 = 0;
#pragma unroll
    for (int q = 0; q < 16; ++q) {
        s0 += stats[q * 4 + 0]; s1 += stats[q * 4 + 1];
        s2 += stats[q * 4 + 2]; s3 += stats[q * 4 + 3];
    }
    const float cntInv = 1.0f / (float)TOTPT;
    const float m0 = s0 * cntInv, m1 = s1 * cntInv;
    const float var0 = s2 * cntInv - m0 * m0;
    const float var1 = s3 * cntInv - m1 * m1;
    const float i0 = rsqrtf(var0 + 1e-5f), i1 = rsqrtf(var1 + 1e-5f);
    const float g0 = pos_g[0], g1 = pos_g[1];
    const float be0 = pos_beta[0], be1 = pos_beta[1];

    float x4a[3], x4b[3];
#pragma unroll
    for (int m3 = 0; m3 < 3; ++m3) {
        const int m   = n + m3 - 1;
        const float msk = (m >= 0 && m < NPTS) ? 1.0f : 0.0f;
        const int mc  = (m < 0) ? 0 : ((m >= NPTS) ? NPTS - 1 : m);
        float y0 = x1[((size_t)b * 2 + 0) * NPTS + mc];
        float y1 = x1[((size_t)b * 2 + 1) * NPTS + mc];
        y0 = g0 * (y0 - m0) * i0 + be0;
        y1 = g1 * (y1 - m1) * i1 + be1;
        y0 = (y0 >= 0.0f) ? y0 : 0.2f * y0;
        y1 = (y1 >= 0.0f) ? y1 : 0.2f * y1;
        const float cv = cosA[(b << 13) + mc];
        const float sv = sinA[(b << 13) + mc];
        x4a[m3] = (y0 * cv - y1 * sv) * msk;
        x4b[m3] = (y0 * sv + y1 * cv) * msk;
    }

    float z0 = ori_b[0], z1 = ori_b[1];
#pragma unroll
    for (int k = 0; k < 3; ++k) {
        z0 += ori_w[0 * 6 + 0 * 3 + k] * x4a[k] + ori_w[0 * 6 + 1 * 3 + k] * x4b[k];
        z1 += ori_w[1 * 6 + 0 * 3 + k] * x4a[k] + ori_w[1 * 6 + 1 * 3 + k] * x4b[k];
    }
    x5[((size_t)b * 2 + 0) * NPTS + n] = z0;
    x5[((size_t)b * 2 + 1) * NPTS + n] = z1;

    block_reduce_atomic4(z0, z1, z0 * z0, z1 * z1,
                         stats + 64 + ((blockIdx.x & 15) << 2));
}

// ---------------------------------------------------------------------------
// Kernel E: BN2 apply -> out
// ---------------------------------------------------------------------------
__global__ __launch_bounds__(256) void kernE(
    const float* __restrict__ x5, const float* __restrict__ stats,
    const float* __restrict__ ori_g, const float* __restrict__ ori_beta,
    float* __restrict__ out)
{
    const int gg = blockIdx.x * 256 + threadIdx.x;  // 0..524287
    const int o = (gg >> 13) & 1;
    float sm = 0, sq = 0;
#pragma unroll
    for (int q = 0; q < 16; ++q) {
        sm += stats[64 + q * 4 + o];
        sq += stats[64 + q * 4 + 2 + o];
    }
    const float cntInv = 1.0f / (float)TOTPT;
    const float m  = sm * cntInv;
    const float vv = sq * cntInv - m * m;
    const float inv = rsqrtf(vv + 1e-5f);
    out[gg] = ori_g[o] * (x5[gg] - m) * inv + ori_beta[o];
}

// ---------------------------------------------------------------------------
extern "C" void kernel_launch(void* const* d_in, const int* in_sizes, int n_in,
                              void* d_out, int out_size, void* d_ws, size_t ws_size,
                              hipStream_t stream)
{
    const float* pts      = (const float*)d_in[0];
    const float* feats    = (const float*)d_in[1];
    const float* rot_w    = (const float*)d_in[2];
    const float* rot_b    = (const float*)d_in[3];
    const float* trans_w  = (const float*)d_in[4];
    const float* trans_b  = (const float*)d_in[5];
    const float* pos_w    = (const float*)d_in[6];
    const float* pos_b    = (const float*)d_in[7];
    const float* pos_g    = (const float*)d_in[8];
    const float* pos_beta = (const float*)d_in[9];
    const float* ori_w    = (const float*)d_in[10];
    const float* ori_b    = (const float*)d_in[11];
    const float* ori_g    = (const float*)d_in[12];
    const float* ori_beta = (const float*)d_in[13];

    float* ws    = (float*)d_ws;
    float* x1    = ws + X1_OFF;
    float* cosA  = ws + COS_OFF;
    float* sinA  = ws + SIN_OFF;
    float* x5    = ws + X5_OFF;
    float* stats = ws + STATS_OFF;

    hipMemsetAsync(stats, 0, 128 * sizeof(float), stream);

    kernAB<<<1024, 256, 0, stream>>>(pts, feats, rot_w, rot_b, trans_w, trans_b,
                                     pos_w, pos_b, x1, cosA, sinA, stats);
    kernD<<<1024, 256, 0, stream>>>(x1, cosA, sinA, pos_g, pos_beta,
                                    ori_w, ori_b, stats, x5);
    kernE<<<2048, 256, 0, stream>>>(x5, stats, ori_g, ori_beta, (float*)d_out);
}